// Round 4
// baseline (429.016 us; speedup 1.0000x reference)
//
#include <hip/hip_runtime.h>

// Problem constants (from reference): B=1, T=8192, H=400, DEPTH=32.
#define HDIM  400
#define TLEN  8192
#define DEPTH 32
#define SLICE  (DEPTH * HDIM)   // 12800 floats per t
#define SLICE4 (SLICE / 4)      // 3200 float4 per t
#define ROW4   (HDIM / 4)       // 100 float4 of val per t
#define VBLOCK 256
#define FBLOCK 320              // 5 waves; 3200 float4 / 320 = exactly 10 per thread

// Kernel 1: one wave (64 lanes) per timestep t.
//   val[t] = softmax(W x_t + b)[0] * sigmoid(D . x_t)
__global__ __launch_bounds__(VBLOCK) void val_kernel(
    const float* __restrict__ hs,   // (T, H)
    const float* __restrict__ W,    // (3, H)
    const float* __restrict__ b,    // (3,)
    const float* __restrict__ D,    // (H,)
    float* __restrict__ val)        // (T,)
{
    const int wave = threadIdx.x >> 6;
    const int lane = threadIdx.x & 63;
    const int t = blockIdx.x * (VBLOCK / 64) + wave;

    const float* __restrict__ x = hs + (size_t)t * HDIM;

    float a0 = 0.f, a1 = 0.f, a2 = 0.f, ad = 0.f;
    for (int i = lane; i < HDIM; i += 64) {
        float h = x[i];
        a0 += h * W[i];
        a1 += h * W[HDIM + i];
        a2 += h * W[2 * HDIM + i];
        ad += h * D[i];
    }

    // XOR butterfly: every lane ends with the total across all 64 lanes.
    #pragma unroll
    for (int off = 32; off > 0; off >>= 1) {
        a0 += __shfl_xor(a0, off);
        a1 += __shfl_xor(a1, off);
        a2 += __shfl_xor(a2, off);
        ad += __shfl_xor(ad, off);
    }

    float l0 = a0 + b[0];
    float l1 = a1 + b[1];
    float l2 = a2 + b[2];
    float m  = fmaxf(l0, fmaxf(l1, l2));
    float e0 = __expf(l0 - m);
    float e1 = __expf(l1 - m);
    float e2 = __expf(l2 - m);
    float p0 = e0 / (e0 + e1 + e2);
    float pv = 1.0f / (1.0f + __expf(-ad));
    float v  = p0 * pv;

    if (lane == 0) val[t] = v;
}

// Kernel 2: one block per timestep slice. t = blockIdx.x is block-uniform, so
// val[t] is a single scalar load; each thread stores exactly 10 float4 at
// stride FBLOCK, fully unrolled — a bare store loop like fillBufferAligned.
// Only the k=0 store carries the row-0 value (tid < 100), the rest are zero.
__global__ __launch_bounds__(FBLOCK) void fill_kernel(
    const float* __restrict__ val,  // (T,)
    float4* __restrict__ out)       // (T, SLICE4)
{
    const int t = blockIdx.x;
    const float vt = val[t];                        // scalar (wave-uniform) load
    float4* __restrict__ o = out + (size_t)t * SLICE4 + threadIdx.x;

    const float v0 = (threadIdx.x < ROW4) ? vt : 0.f;
    o[0] = make_float4(v0, v0, v0, v0);
    const float4 z = make_float4(0.f, 0.f, 0.f, 0.f);
    #pragma unroll
    for (int k = 1; k < SLICE4 / FBLOCK; ++k) {
        o[(size_t)k * FBLOCK] = z;
    }
}

extern "C" void kernel_launch(void* const* d_in, const int* in_sizes, int n_in,
                              void* d_out, int out_size, void* d_ws, size_t ws_size,
                              hipStream_t stream) {
    const float* hs = (const float*)d_in[0];  // (1, 8192, 400)
    const float* W  = (const float*)d_in[1];  // (3, 400)
    const float* b  = (const float*)d_in[2];  // (3,)
    const float* D  = (const float*)d_in[3];  // (1, 400)
    float* out = (float*)d_out;               // (1, 8192, 32, 400)
    float* val = (float*)d_ws;                // 8192 floats of scratch

    val_kernel<<<TLEN / (VBLOCK / 64), VBLOCK, 0, stream>>>(hs, W, b, D, val);
    fill_kernel<<<TLEN, FBLOCK, 0, stream>>>(val, (float4*)out);
}